// Round 2
// baseline (29031.946 us; speedup 1.0000x reference)
//
#include <hip/hip_runtime.h>
#include <hip/hip_bf16.h>

#define B_   8
#define D_   256
#define T_   4096
#define Q_   8
#define K_   1024
#define BT_  (B_*T_)            // 32768 rows
#define N_   (B_*T_*D_)         // 8388608 elements
#define LOSS_OFF N_
#define IDX_OFF  (N_+1)
#define OUT_N (N_ + 1 + Q_*BT_) // 8650753 floats

// ---------------- init kernels ----------------

__global__ void k_zero_out(float* out) {
    int i = blockIdx.x * 256 + threadIdx.x;
    if (i < OUT_N) out[i] = 0.0f;
}

__global__ void k_init_residual(const float* __restrict__ z,
                                float* __restrict__ residual,
                                double* lossAcc) {
    int i = blockIdx.x * 256 + threadIdx.x;       // exactly N_ threads
    int d  = i & (D_ - 1);
    int bt = i >> 8;
    int t  = bt & (T_ - 1);
    int b  = bt >> 12;
    residual[i] = z[((size_t)(b * D_ + d)) * T_ + t];   // transpose [B,D,T]->[B,T,D]
    if (i == 0) *lossAcc = 0.0;
}

// S_e[q][k] = fp64 sum of fl32(e^2), rounded to f32
__global__ void k_se(const float* __restrict__ cb, float* __restrict__ Se) {
    int i = blockIdx.x * 256 + threadIdx.x;
    if (i >= Q_ * K_) return;
    const float* e = cb + (size_t)i * D_;
    double s = 0.0;
    for (int d = 0; d < D_; ++d) {
        float v = e[d];
        float a = v * v;           // square in f32 first, like the reference
        s += (double)a;
    }
    Se[i] = (float)s;
}

// ---------------- per-stage kernel: one block per (b,t) row ----------------

__launch_bounds__(256)
__global__ void k_stage(const float* __restrict__ cb,
                        const float* __restrict__ Se,
                        float* __restrict__ residual,
                        float* __restrict__ out,
                        double* __restrict__ lossAcc,
                        int q) {
    __shared__ double r64[256];
    __shared__ double dsh[256];
    __shared__ float  sd[256];
    __shared__ int    sk[256];
    __shared__ float  srb;

    const int row = blockIdx.x;          // row = b*T + t
    const int tid = threadIdx.x;
    const int base = row * D_ + tid;

    float rv = residual[base];
    r64[tid] = (double)rv;
    dsh[tid] = (double)(rv * rv);        // f32 square, f64 accumulate
    __syncthreads();

    // ||r||^2 in fp64 -> f32 (accurate; argmin order is shift-invariant)
    for (int s = 128; s > 0; s >>= 1) {
        if (tid < s) dsh[tid] += dsh[tid + s];
        __syncthreads();
    }
    if (tid == 0) srb = (float)dsh[0];
    __syncthreads();
    const float Sr = srb;

    const float* Eq  = cb + (size_t)q * K_ * D_;
    const float* Seq = Se + q * K_;

    float bestd = 3.4e38f;
    int   bestk = K_;

    for (int c = 0; c < 4; ++c) {
        int k = (c << 8) + tid;
        const float4* E4 = (const float4*)(Eq + (size_t)k * D_);
        double acc = 0.0;
        #pragma unroll 8
        for (int i2 = 0; i2 < 64; ++i2) {
            float4 v = E4[i2];
            acc = fma((double)v.x, r64[4*i2+0], acc);
            acc = fma((double)v.y, r64[4*i2+1], acc);
            acc = fma((double)v.z, r64[4*i2+2], acc);
            acc = fma((double)v.w, r64[4*i2+3], acc);
        }
        float dotf = (float)acc;                 // correctly-rounded f32 dot
        float V  = Sr + Seq[k];                  // fl(S_r + S_e)
        float dd = V - 2.0f * dotf;              // fl(V - 2*dot)  (2*dot exact)
        if (dd < bestd || (dd == bestd && k < bestk)) { bestd = dd; bestk = k; }
    }

    // block argmin with first-index (lowest k) tie-break
    sd[tid] = bestd; sk[tid] = bestk;
    __syncthreads();
    for (int s = 128; s > 0; s >>= 1) {
        if (tid < s) {
            float od = sd[tid + s]; int ok = sk[tid + s];
            if (od < sd[tid] || (od == sd[tid] && ok < sk[tid])) {
                sd[tid] = od; sk[tid] = ok;
            }
        }
        __syncthreads();
    }
    const int idx = sk[0];

    // straight-through update, exact fp32 elementwise (matches reference bitwise)
    float zq   = Eq[(size_t)idx * D_ + tid];
    float t1   = zq - rv;          // fl(z_q - r)
    float zqst = rv + t1;          // fl(r + fl(z_q - r))  == z_q_st forward value
    float rnew = rv - zqst;        // fl(r - z_q_st)
    residual[base] = rnew;

    // loss contribution: (z_q - residual)^2
    dsh[tid] = (double)t1 * (double)t1;

    // quantized_out accumulation in fp32 (matches reference's add order)
    int b = row >> 12, t = row & (T_ - 1);
    int pos = (b * D_ + tid) * T_ + t;
    out[pos] = out[pos] + zqst;

    if (tid == 0)
        out[IDX_OFF + q * BT_ + row] = (float)idx;

    __syncthreads();
    for (int s = 128; s > 0; s >>= 1) {
        if (tid < s) dsh[tid] += dsh[tid + s];
        __syncthreads();
    }
    if (tid == 0) atomicAdd(lossAcc, dsh[0]);
}

__global__ void k_final(const double* lossAcc, float* out) {
    if (threadIdx.x == 0 && blockIdx.x == 0) {
        double m = *lossAcc / (double)N_;
        out[LOSS_OFF] = (float)(1.25 * m);
    }
}

// ---------------- launcher ----------------

extern "C" void kernel_launch(void* const* d_in, const int* in_sizes, int n_in,
                              void* d_out, int out_size, void* d_ws, size_t ws_size,
                              hipStream_t stream) {
    const float* z  = (const float*)d_in[0];
    const float* cb = (const float*)d_in[1];
    float* out = (float*)d_out;

    // workspace layout: residual f32 [N_] | S_e f32 [Q*K] | loss double
    float*  residual = (float*)d_ws;
    float*  Se       = (float*)((char*)d_ws + (size_t)N_ * 4);
    double* lossAcc  = (double*)((char*)d_ws + (size_t)N_ * 4 + (size_t)Q_ * K_ * 4);

    hipLaunchKernelGGL(k_zero_out, dim3((OUT_N + 255) / 256), dim3(256), 0, stream, out);
    hipLaunchKernelGGL(k_init_residual, dim3(N_ / 256), dim3(256), 0, stream,
                       z, residual, lossAcc);
    hipLaunchKernelGGL(k_se, dim3((Q_ * K_ + 255) / 256), dim3(256), 0, stream, cb, Se);
    for (int q = 0; q < Q_; ++q) {
        hipLaunchKernelGGL(k_stage, dim3(BT_), dim3(256), 0, stream,
                           cb, Se, residual, out, lossAcc, q);
    }
    hipLaunchKernelGGL(k_final, dim3(1), dim3(256), 0, stream, lossAcc, out);
}

// Round 3
// 16184.767 us; speedup vs baseline: 1.7938x; 1.7938x over previous
//
#include <hip/hip_runtime.h>
#include <hip/hip_bf16.h>

#define B_   8
#define D_   256
#define T_   4096
#define Q_   8
#define K_   1024
#define BT_  (B_*T_)            // 32768 rows
#define N_   (B_*T_*D_)         // 8388608 elements
#define LOSS_OFF N_
#define IDX_OFF  (N_+1)
#define OUT_N (N_ + 1 + Q_*BT_) // 8650753 floats
#define R_   4                  // rows per block
#define C_   4                  // candidates per thread (K_/256)

// ---------------- init kernels ----------------

__global__ void k_zero_out(float* out) {
    int i = blockIdx.x * 256 + threadIdx.x;
    if (i < OUT_N) out[i] = 0.0f;
}

__global__ void k_init_residual(const float* __restrict__ z,
                                float* __restrict__ residual,
                                double* lossAcc) {
    int i = blockIdx.x * 256 + threadIdx.x;       // exactly N_ threads
    int d  = i & (D_ - 1);
    int bt = i >> 8;
    int t  = bt & (T_ - 1);
    int b  = bt >> 12;
    residual[i] = z[((size_t)(b * D_ + d)) * T_ + t];   // transpose [B,D,T]->[B,T,D]
    if (i == 0) *lossAcc = 0.0;
}

// S_e[q][k] = fp64 sum of fl32(e^2), rounded to f32
__global__ void k_se(const float* __restrict__ cb, float* __restrict__ Se) {
    int i = blockIdx.x * 256 + threadIdx.x;
    if (i >= Q_ * K_) return;
    const float* e = cb + (size_t)i * D_;
    double s = 0.0;
    for (int d = 0; d < D_; ++d) {
        float v = e[d];
        float a = v * v;           // square in f32 first, like the reference
        s += (double)a;
    }
    Se[i] = (float)s;
}

// ---------------- per-stage kernel: R_ rows per block ----------------

__launch_bounds__(256)
__global__ void k_stage(const float* __restrict__ cb,
                        const float* __restrict__ Se,
                        float* __restrict__ residual,
                        float* __restrict__ out,
                        double* __restrict__ lossAcc,
                        int q) {
    __shared__ double r64[R_][256];
    __shared__ double dsh[R_][256];
    __shared__ float  sd[R_][256];
    __shared__ int    sk[R_][256];
    __shared__ float  srb[R_];

    const int row0 = blockIdx.x * R_;    // 4 consecutive (b,t) rows, same b
    const int tid  = threadIdx.x;

    float rv[R_];
    #pragma unroll
    for (int j = 0; j < R_; ++j) {
        rv[j] = residual[(size_t)(row0 + j) * D_ + tid];
        r64[j][tid] = (double)rv[j];
        dsh[j][tid] = (double)(rv[j] * rv[j]);   // f32 square, f64 accumulate
    }
    __syncthreads();

    // ||r||^2 per row: fp64 tree (same order as before -> identical values)
    for (int s = 128; s > 0; s >>= 1) {
        if (tid < s) {
            #pragma unroll
            for (int j = 0; j < R_; ++j) dsh[j][tid] += dsh[j][tid + s];
        }
        __syncthreads();
    }
    if (tid < R_) srb[tid] = (float)dsh[tid][0];
    __syncthreads();

    const float*  Eq  = cb + (size_t)q * K_ * D_;
    const float*  Seq = Se + q * K_;
    const float4* E4  = (const float4*)Eq;

    // 16 independent fp64 accumulator chains: [candidate][row]
    double acc[C_][R_];
    #pragma unroll
    for (int c = 0; c < C_; ++c)
        #pragma unroll
        for (int j = 0; j < R_; ++j) acc[c][j] = 0.0;

    for (int i2 = 0; i2 < 64; ++i2) {
        double rr[R_][4];
        #pragma unroll
        for (int j = 0; j < R_; ++j) {
            double2 p0 = *(const double2*)&r64[j][4 * i2];
            double2 p1 = *(const double2*)&r64[j][4 * i2 + 2];
            rr[j][0] = p0.x; rr[j][1] = p0.y; rr[j][2] = p1.x; rr[j][3] = p1.y;
        }
        float4 ev[C_];
        #pragma unroll
        for (int c = 0; c < C_; ++c)
            ev[c] = E4[(size_t)(c * 256 + tid) * 64 + i2];
        #pragma unroll
        for (int c = 0; c < C_; ++c) {
            #pragma unroll
            for (int j = 0; j < R_; ++j) {
                // same term order as before: x,y,z,w sequential per chain
                acc[c][j] = fma((double)ev[c].x, rr[j][0], acc[c][j]);
                acc[c][j] = fma((double)ev[c].y, rr[j][1], acc[c][j]);
                acc[c][j] = fma((double)ev[c].z, rr[j][2], acc[c][j]);
                acc[c][j] = fma((double)ev[c].w, rr[j][3], acc[c][j]);
            }
        }
    }

    float bestd[R_]; int bestk[R_];
    #pragma unroll
    for (int j = 0; j < R_; ++j) { bestd[j] = 3.4e38f; bestk[j] = K_; }

    #pragma unroll
    for (int c = 0; c < C_; ++c) {
        int k = c * 256 + tid;
        float se = Seq[k];
        #pragma unroll
        for (int j = 0; j < R_; ++j) {
            float dotf = (float)acc[c][j];          // correctly-rounded f32 dot
            float V  = srb[j] + se;                 // fl(S_r + S_e)
            float dd = V - 2.0f * dotf;             // fl(V - 2*dot)
            if (dd < bestd[j] || (dd == bestd[j] && k < bestk[j])) {
                bestd[j] = dd; bestk[j] = k;
            }
        }
    }

    // block argmin per row, first-index tie-break
    #pragma unroll
    for (int j = 0; j < R_; ++j) { sd[j][tid] = bestd[j]; sk[j][tid] = bestk[j]; }
    __syncthreads();
    for (int s = 128; s > 0; s >>= 1) {
        if (tid < s) {
            #pragma unroll
            for (int j = 0; j < R_; ++j) {
                float od = sd[j][tid + s]; int ok = sk[j][tid + s];
                if (od < sd[j][tid] || (od == sd[j][tid] && ok < sk[j][tid])) {
                    sd[j][tid] = od; sk[j][tid] = ok;
                }
            }
        }
        __syncthreads();
    }

    // epilogue: exact fp32 STE updates per row
    double lsum = 0.0;
    #pragma unroll
    for (int j = 0; j < R_; ++j) {
        const int idx = sk[j][0];
        const int row = row0 + j;
        float zq   = Eq[(size_t)idx * D_ + tid];
        float t1   = zq - rv[j];          // fl(z_q - r)
        float zqst = rv[j] + t1;          // fl(r + fl(z_q - r))
        residual[(size_t)row * D_ + tid] = rv[j] - zqst;
        lsum += (double)t1 * (double)t1;
        int b = row >> 12, t = row & (T_ - 1);
        int pos = (b * D_ + tid) * T_ + t;
        out[pos] = out[pos] + zqst;
        if (tid == 0) out[IDX_OFF + q * BT_ + row] = (float)idx;
    }

    __syncthreads();
    dsh[0][tid] = lsum;
    __syncthreads();
    for (int s = 128; s > 0; s >>= 1) {
        if (tid < s) dsh[0][tid] += dsh[0][tid + s];
        __syncthreads();
    }
    if (tid == 0) atomicAdd(lossAcc, dsh[0][0]);
}

__global__ void k_final(const double* lossAcc, float* out) {
    if (threadIdx.x == 0 && blockIdx.x == 0) {
        double m = *lossAcc / (double)N_;
        out[LOSS_OFF] = (float)(1.25 * m);
    }
}

// ---------------- launcher ----------------

extern "C" void kernel_launch(void* const* d_in, const int* in_sizes, int n_in,
                              void* d_out, int out_size, void* d_ws, size_t ws_size,
                              hipStream_t stream) {
    const float* z  = (const float*)d_in[0];
    const float* cb = (const float*)d_in[1];
    float* out = (float*)d_out;

    // workspace layout: residual f32 [N_] | S_e f32 [Q*K] | loss double
    float*  residual = (float*)d_ws;
    float*  Se       = (float*)((char*)d_ws + (size_t)N_ * 4);
    double* lossAcc  = (double*)((char*)d_ws + (size_t)N_ * 4 + (size_t)Q_ * K_ * 4);

    hipLaunchKernelGGL(k_zero_out, dim3((OUT_N + 255) / 256), dim3(256), 0, stream, out);
    hipLaunchKernelGGL(k_init_residual, dim3(N_ / 256), dim3(256), 0, stream,
                       z, residual, lossAcc);
    hipLaunchKernelGGL(k_se, dim3((Q_ * K_ + 255) / 256), dim3(256), 0, stream, cb, Se);
    for (int q = 0; q < Q_; ++q) {
        hipLaunchKernelGGL(k_stage, dim3(BT_ / R_), dim3(256), 0, stream,
                           cb, Se, residual, out, lossAcc, q);
    }
    hipLaunchKernelGGL(k_final, dim3(1), dim3(256), 0, stream, lossAcc, out);
}

// Round 4
// 3165.829 us; speedup vs baseline: 9.1704x; 5.1123x over previous
//
#include <hip/hip_runtime.h>

#define B_   8
#define D_   256
#define T_   4096
#define Q_   8
#define K_   1024
#define BT_  (B_*T_)            // 32768 rows
#define N_   (B_*T_*D_)         // 8388608 elements
#define LOSS_OFF N_
#define IDX_OFF  (N_+1)
#define R_   8                  // rows per block
#define C_   4                  // candidates per thread: 4*tid .. 4*tid+3

// ---------------- init: z [B,D,T] -> residual [B,T,D], tiled transpose ----------------

__global__ void k_init(const float* __restrict__ z, float* __restrict__ residual,
                       double* lossAcc) {
    __shared__ float tile[32][33];
    int b  = blockIdx.z;
    int d0 = blockIdx.y * 32;
    int t0 = blockIdx.x * 32;
    int tx = threadIdx.x & 31;
    int ty = threadIdx.x >> 5;
    const float* zb = z + (size_t)b * D_ * T_;
    #pragma unroll
    for (int r = 0; r < 32; r += 8)
        tile[ty + r][tx] = zb[(size_t)(d0 + ty + r) * T_ + t0 + tx];   // tile[d][t]
    __syncthreads();
    float* rb = residual + (size_t)b * T_ * D_;
    #pragma unroll
    for (int r = 0; r < 32; r += 8)
        rb[(size_t)(t0 + ty + r) * D_ + d0 + tx] = tile[tx][ty + r];
    if (b == 0 && blockIdx.x == 0 && blockIdx.y == 0 && threadIdx.x == 0)
        *lossAcc = 0.0;
}

// ---------------- codebook transpose: cb [Q,K,D] -> Et [Q,D,K] ----------------

__global__ void k_et(const float* __restrict__ cb, float* __restrict__ Et) {
    __shared__ float tile[32][33];
    int q  = blockIdx.z;
    int k0 = blockIdx.y * 32;
    int d0 = blockIdx.x * 32;
    int tx = threadIdx.x & 31;
    int ty = threadIdx.x >> 5;
    const float* cq = cb + (size_t)q * K_ * D_;
    #pragma unroll
    for (int r = 0; r < 32; r += 8)
        tile[ty + r][tx] = cq[(size_t)(k0 + ty + r) * D_ + d0 + tx];   // tile[k][d]
    __syncthreads();
    float* eq = Et + (size_t)q * D_ * K_;
    #pragma unroll
    for (int r = 0; r < 32; r += 8)
        eq[(size_t)(d0 + ty + r) * K_ + k0 + tx] = tile[tx][ty + r];
}

// ---------------- S_e: fp64 sum of fl32(e^2), rounded to f32 ----------------

__global__ void k_se(const float* __restrict__ cb, float* __restrict__ Se) {
    int i = blockIdx.x * 256 + threadIdx.x;
    if (i >= Q_ * K_) return;
    const float* e = cb + (size_t)i * D_;
    double s = 0.0;
    for (int d = 0; d < D_; ++d) {
        float v = e[d];
        float a = v * v;
        s += (double)a;
    }
    Se[i] = (float)s;
}

// ---------------- per-stage kernel: R_ rows/block, coalesced Et reads ----------------

__launch_bounds__(256)
__global__ void k_stage(const float* __restrict__ cb,
                        const float* __restrict__ Et,
                        const float* __restrict__ Se,
                        float* __restrict__ residual,
                        float* __restrict__ out,
                        double* __restrict__ lossAcc,
                        int q) {
    __shared__ double r64T[D_][R_];                    // 16 KB, [d][row] -> 64B broadcast/iter
    __shared__ union {
        double dsh[R_][256];                           // prologue ||r||^2 + epilogue loss
        struct { float sd[R_][256]; int sk[R_][256]; } am;   // argmin phase
    } u;
    __shared__ float srb[R_];
    __shared__ int   sidx[R_];

    const int row0 = blockIdx.x * R_;
    const int tid  = threadIdx.x;

    float rv[R_];
    #pragma unroll
    for (int j = 0; j < R_; ++j) {
        rv[j] = residual[(size_t)(row0 + j) * D_ + tid];
        r64T[tid][j] = (double)rv[j];
        u.dsh[j][tid] = (double)(rv[j] * rv[j]);       // f32 square, f64 accumulate
    }
    __syncthreads();

    // ||r||^2 per row: fp64 tree, same order as prior (passing) rounds
    for (int s = 128; s > 0; s >>= 1) {
        if (tid < s) {
            #pragma unroll
            for (int j = 0; j < R_; ++j) u.dsh[j][tid] += u.dsh[j][tid + s];
        }
        __syncthreads();
    }
    if (tid < R_) srb[tid] = (float)u.dsh[tid][0];
    __syncthreads();

    const float4* Et4 = (const float4*)(Et + (size_t)q * D_ * K_);

    // 32 independent fp64 chains: [candidate][row]; per-candidate order = d ascending
    double acc[C_][R_];
    #pragma unroll
    for (int c = 0; c < C_; ++c)
        #pragma unroll
        for (int j = 0; j < R_; ++j) acc[c][j] = 0.0;

    #pragma unroll 2
    for (int d = 0; d < D_; ++d) {
        float4 ev = Et4[(size_t)d * (K_ / 4) + tid];   // coalesced: 1KB/wave
        double e[4];
        e[0] = (double)ev.x; e[1] = (double)ev.y;
        e[2] = (double)ev.z; e[3] = (double)ev.w;
        double rr[R_];
        #pragma unroll
        for (int j = 0; j < R_; ++j) rr[j] = r64T[d][j];   // 64B LDS broadcast
        #pragma unroll
        for (int c = 0; c < C_; ++c)
            #pragma unroll
            for (int j = 0; j < R_; ++j)
                acc[c][j] = fma(e[c], rr[j], acc[c][j]);
    }

    // distances + per-thread argmin (candidates ascending -> first-index tie-break)
    float bestd[R_]; int bestk[R_];
    #pragma unroll
    for (int j = 0; j < R_; ++j) { bestd[j] = 3.4e38f; bestk[j] = K_; }
    #pragma unroll
    for (int c = 0; c < C_; ++c) {
        int k = 4 * tid + c;
        float se = Se[q * K_ + k];
        #pragma unroll
        for (int j = 0; j < R_; ++j) {
            float dotf = (float)acc[c][j];             // correctly-rounded f32 dot
            float V  = srb[j] + se;                    // fl(S_r + S_e)
            float dd = V - 2.0f * dotf;                // fl(V - 2*dot)
            if (dd < bestd[j] || (dd == bestd[j] && k < bestk[j])) {
                bestd[j] = dd; bestk[j] = k;
            }
        }
    }

    // block argmin per row, first-index tie-break
    #pragma unroll
    for (int j = 0; j < R_; ++j) { u.am.sd[j][tid] = bestd[j]; u.am.sk[j][tid] = bestk[j]; }
    __syncthreads();
    for (int s = 128; s > 0; s >>= 1) {
        if (tid < s) {
            #pragma unroll
            for (int j = 0; j < R_; ++j) {
                float od = u.am.sd[j][tid + s]; int ok = u.am.sk[j][tid + s];
                if (od < u.am.sd[j][tid] || (od == u.am.sd[j][tid] && ok < u.am.sk[j][tid])) {
                    u.am.sd[j][tid] = od; u.am.sk[j][tid] = ok;
                }
            }
        }
        __syncthreads();
    }
    if (tid < R_) sidx[tid] = u.am.sk[tid][0];
    __syncthreads();

    // epilogue: exact fp32 STE residual update (bitwise as before); no out scatter
    const float* Eq = cb + (size_t)q * K_ * D_;
    double lsum = 0.0;
    #pragma unroll
    for (int j = 0; j < R_; ++j) {
        int idx = sidx[j];
        float zq   = Eq[(size_t)idx * D_ + tid];       // coalesced gather
        float t1   = zq - rv[j];                       // fl(z_q - r)
        float zqst = rv[j] + t1;                       // fl(r + fl(z_q - r))
        residual[(size_t)(row0 + j) * D_ + tid] = rv[j] - zqst;
        lsum += (double)t1 * (double)t1;
    }
    if (tid < R_) out[IDX_OFF + q * BT_ + row0 + tid] = (float)sidx[tid];

    __syncthreads();
    u.dsh[0][tid] = lsum;
    __syncthreads();
    for (int s = 128; s > 0; s >>= 1) {
        if (tid < s) u.dsh[0][tid] += u.dsh[0][tid + s];
        __syncthreads();
    }
    if (tid == 0) atomicAdd(lossAcc, u.dsh[0][0]);
}

// ---------------- emit: out[b,d,t] = z[b,d,t] - r_final[b,t,d] (tiled transpose) ----------------

__global__ void k_emit(const float* __restrict__ z, const float* __restrict__ residual,
                       float* __restrict__ out) {
    __shared__ float tile[32][33];
    int b  = blockIdx.z;
    int t0 = blockIdx.y * 32;
    int d0 = blockIdx.x * 32;
    int tx = threadIdx.x & 31;
    int ty = threadIdx.x >> 5;
    const float* rb = residual + (size_t)b * T_ * D_;
    #pragma unroll
    for (int r = 0; r < 32; r += 8)
        tile[ty + r][tx] = rb[(size_t)(t0 + ty + r) * D_ + d0 + tx];   // tile[t][d]
    __syncthreads();
    const float* zb = z + (size_t)b * D_ * T_;
    float* ob = out + (size_t)b * D_ * T_;
    #pragma unroll
    for (int r = 0; r < 32; r += 8) {
        size_t off = (size_t)(d0 + ty + r) * T_ + t0 + tx;
        ob[off] = zb[off] - tile[tx][ty + r];
    }
}

__global__ void k_final(const double* lossAcc, float* out) {
    if (threadIdx.x == 0 && blockIdx.x == 0) {
        double m = *lossAcc / (double)N_;
        out[LOSS_OFF] = (float)(1.25 * m);
    }
}

// ---------------- launcher ----------------

extern "C" void kernel_launch(void* const* d_in, const int* in_sizes, int n_in,
                              void* d_out, int out_size, void* d_ws, size_t ws_size,
                              hipStream_t stream) {
    const float* z  = (const float*)d_in[0];
    const float* cb = (const float*)d_in[1];
    float* out = (float*)d_out;

    // ws layout: residual f32[N_] | Et f32[Q*D*K] (8MB) | Se f32[Q*K] | loss double
    float*  residual = (float*)d_ws;
    float*  Et       = (float*)((char*)d_ws + (size_t)N_ * 4);
    float*  Se       = (float*)((char*)d_ws + (size_t)N_ * 4 + (size_t)Q_ * D_ * K_ * 4);
    double* lossAcc  = (double*)((char*)d_ws + (size_t)N_ * 4 + (size_t)Q_ * D_ * K_ * 4
                                 + (size_t)Q_ * K_ * 4);

    hipLaunchKernelGGL(k_init, dim3(T_ / 32, D_ / 32, B_), dim3(256), 0, stream,
                       z, residual, lossAcc);
    hipLaunchKernelGGL(k_et, dim3(D_ / 32, K_ / 32, Q_), dim3(256), 0, stream, cb, Et);
    hipLaunchKernelGGL(k_se, dim3((Q_ * K_ + 255) / 256), dim3(256), 0, stream, cb, Se);
    for (int q = 0; q < Q_; ++q) {
        hipLaunchKernelGGL(k_stage, dim3(BT_ / R_), dim3(256), 0, stream,
                           cb, Et, Se, residual, out, lossAcc, q);
    }
    hipLaunchKernelGGL(k_emit, dim3(D_ / 32, T_ / 32, B_), dim3(256), 0, stream,
                       z, residual, out);
    hipLaunchKernelGGL(k_final, dim3(1), dim3(256), 0, stream, lossAcc, out);
}

// Round 5
// 1985.186 us; speedup vs baseline: 14.6243x; 1.5947x over previous
//
#include <hip/hip_runtime.h>

#define B_   8
#define D_   256
#define T_   4096
#define Q_   8
#define K_   1024
#define BT_  (B_*T_)            // 32768 rows
#define N_   (B_*T_*D_)         // 8388608 elements
#define LOSS_OFF N_
#define IDX_OFF  (N_+1)
#define R_   16                 // rows per block
#define C_   4                  // candidates per thread: 4*tid .. 4*tid+3

// ---------------- init: z [B,D,T] -> residual [B,T,D], tiled transpose ----------------

__global__ void k_init(const float* __restrict__ z, float* __restrict__ residual,
                       double* lossAcc) {
    __shared__ float tile[32][33];
    int b  = blockIdx.z;
    int d0 = blockIdx.y * 32;
    int t0 = blockIdx.x * 32;
    int tx = threadIdx.x & 31;
    int ty = threadIdx.x >> 5;
    const float* zb = z + (size_t)b * D_ * T_;
    #pragma unroll
    for (int r = 0; r < 32; r += 8)
        tile[ty + r][tx] = zb[(size_t)(d0 + ty + r) * T_ + t0 + tx];   // tile[d][t]
    __syncthreads();
    float* rb = residual + (size_t)b * T_ * D_;
    #pragma unroll
    for (int r = 0; r < 32; r += 8)
        rb[(size_t)(t0 + ty + r) * D_ + d0 + tx] = tile[tx][ty + r];
    if (b == 0 && blockIdx.x == 0 && blockIdx.y == 0 && threadIdx.x == 0)
        *lossAcc = 0.0;
}

// ---------------- codebook transpose: cb [Q,K,D] -> Et [Q,D,K] ----------------

__global__ void k_et(const float* __restrict__ cb, float* __restrict__ Et) {
    __shared__ float tile[32][33];
    int q  = blockIdx.z;
    int k0 = blockIdx.y * 32;
    int d0 = blockIdx.x * 32;
    int tx = threadIdx.x & 31;
    int ty = threadIdx.x >> 5;
    const float* cq = cb + (size_t)q * K_ * D_;
    #pragma unroll
    for (int r = 0; r < 32; r += 8)
        tile[ty + r][tx] = cq[(size_t)(k0 + ty + r) * D_ + d0 + tx];   // tile[k][d]
    __syncthreads();
    float* eq = Et + (size_t)q * D_ * K_;
    #pragma unroll
    for (int r = 0; r < 32; r += 8)
        eq[(size_t)(d0 + ty + r) * K_ + k0 + tx] = tile[tx][ty + r];
}

// ---------------- S_e: fp64 sum of fl32(e^2), rounded to f32 ----------------

__global__ void k_se(const float* __restrict__ cb, float* __restrict__ Se) {
    int i = blockIdx.x * 256 + threadIdx.x;
    if (i >= Q_ * K_) return;
    const float* e = cb + (size_t)i * D_;
    double s = 0.0;
    for (int d = 0; d < D_; ++d) {
        float v = e[d];
        float a = v * v;
        s += (double)a;
    }
    Se[i] = (float)s;
}

// ---------------- per-stage kernel: f32 filter + guaranteed fp64 re-rank ----------------

__launch_bounds__(256)
__global__ void k_stage(const float* __restrict__ cb,
                        const float* __restrict__ Et,
                        const float* __restrict__ Se,
                        float* __restrict__ residual,
                        float* __restrict__ out,
                        double* __restrict__ lossAcc,
                        int q) {
    __shared__ float r32T[D_][R_];                    // 16 KB, [d][row]
    __shared__ union {
        double d8[8][256];                            // 16 KB: Sr trees, loss tree
        float  f8[8][256];                            // Sabs trees, min trees, fallback
    } u;
    __shared__ float srb[R_], sab[R_], smin[R_], smu[R_];
    __shared__ int   scount[R_], sidx[R_];
    __shared__ int   slist[R_][16];
    __shared__ float sdd[R_][16];

    const int row0 = blockIdx.x * R_;
    const int tid  = threadIdx.x;

    // load residual rows (coalesced), stash transposed in LDS
    #pragma unroll
    for (int j = 0; j < R_; ++j)
        r32T[tid][j] = residual[(size_t)(row0 + j) * D_ + tid];

    // ||r||^2 per row: fp64 tree, bitwise-identical to prior passing rounds
    for (int h = 0; h < 2; ++h) {
        #pragma unroll
        for (int jj = 0; jj < 8; ++jj) {
            float g = r32T[tid][h * 8 + jj];
            u.d8[jj][tid] = (double)(g * g);
        }
        __syncthreads();
        for (int s = 128; s > 0; s >>= 1) {
            if (tid < s) {
                #pragma unroll
                for (int jj = 0; jj < 8; ++jj) u.d8[jj][tid] += u.d8[jj][tid + s];
            }
            __syncthreads();
        }
        if (tid < 8) srb[h * 8 + tid] = (float)u.d8[tid][0];
        __syncthreads();
    }
    // Sum |r| per row (f32; only feeds the safety margin)
    for (int h = 0; h < 2; ++h) {
        #pragma unroll
        for (int jj = 0; jj < 8; ++jj)
            u.f8[jj][tid] = fabsf(r32T[tid][h * 8 + jj]);
        __syncthreads();
        for (int s = 128; s > 0; s >>= 1) {
            if (tid < s) {
                #pragma unroll
                for (int jj = 0; jj < 8; ++jj) u.f8[jj][tid] += u.f8[jj][tid + s];
            }
            __syncthreads();
        }
        if (tid < 8) sab[h * 8 + tid] = u.f8[tid][0] * 1.001f;
        __syncthreads();
    }
    // per-row margin: 16x the rigorous f32-dot error bound + 8-ulp grid slack
    if (tid < R_) smu[tid] = 9.6e-7f * srb[tid] + 2.4e-7f * sab[tid] + 1e-4f;
    __syncthreads();

    const float4* Et4 = (const float4*)(Et + (size_t)q * D_ * K_);

    // f32 filter: 64 independent chains [cand][row], per-candidate order = d ascending
    float acc[C_][R_];
    #pragma unroll
    for (int c = 0; c < C_; ++c)
        #pragma unroll
        for (int j = 0; j < R_; ++j) acc[c][j] = 0.0f;

    for (int d = 0; d < D_; ++d) {
        float4 ev = Et4[(size_t)d * (K_ / 4) + tid];   // coalesced 1KB/wave
        float e0 = ev.x, e1 = ev.y, e2 = ev.z, e3 = ev.w;
        float rr[R_];
        #pragma unroll
        for (int j = 0; j < R_; ++j) rr[j] = r32T[d][j];   // 64B LDS broadcast
        #pragma unroll
        for (int j = 0; j < R_; ++j) {
            acc[0][j] = fmaf(e0, rr[j], acc[0][j]);
            acc[1][j] = fmaf(e1, rr[j], acc[1][j]);
            acc[2][j] = fmaf(e2, rr[j], acc[2][j]);
            acc[3][j] = fmaf(e3, rr[j], acc[3][j]);
        }
    }

    float4 se4 = ((const float4*)(Se + q * K_))[tid];  // Se[4*tid .. 4*tid+3]
    float sea[C_] = {se4.x, se4.y, se4.z, se4.w};
    float srbr[R_];
    #pragma unroll
    for (int j = 0; j < R_; ++j) srbr[j] = srb[j];

    // per-thread min of approx dd per row
    float bestd[R_];
    #pragma unroll
    for (int j = 0; j < R_; ++j) bestd[j] = 3.4e38f;
    #pragma unroll
    for (int c = 0; c < C_; ++c)
        #pragma unroll
        for (int j = 0; j < R_; ++j) {
            float ddf = (srbr[j] + sea[c]) - 2.0f * acc[c][j];
            bestd[j] = fminf(bestd[j], ddf);
        }

    // block min per row (value only)
    for (int h = 0; h < 2; ++h) {
        #pragma unroll
        for (int jj = 0; jj < 8; ++jj) u.f8[jj][tid] = bestd[h * 8 + jj];
        __syncthreads();
        for (int s = 128; s > 0; s >>= 1) {
            if (tid < s) {
                #pragma unroll
                for (int jj = 0; jj < 8; ++jj)
                    u.f8[jj][tid] = fminf(u.f8[jj][tid], u.f8[jj][tid + s]);
            }
            __syncthreads();
        }
        if (tid < 8) smin[h * 8 + tid] = u.f8[tid][0];
        __syncthreads();
    }

    // survivor collection: every candidate within [min, min+mu] could be the true argmin
    if (tid < R_) scount[tid] = 0;
    __syncthreads();
    #pragma unroll
    for (int c = 0; c < C_; ++c) {
        int k = 4 * tid + c;
        #pragma unroll
        for (int j = 0; j < R_; ++j) {
            float ddf = (srbr[j] + sea[c]) - 2.0f * acc[c][j];
            if (ddf <= smin[j] + smu[j]) {
                int p = atomicAdd(&scount[j], 1);
                if (p < 16) slist[j][p] = k;
            }
        }
    }
    __syncthreads();

    // exact fp64 re-rank of survivors (rows with 2..16 survivors)
    {
        int j = tid >> 4, s = tid & 15;
        int cnt = scount[j];
        if (cnt >= 2 && cnt <= 16 && s < cnt) {
            int k = slist[j][s];
            const float* Ek = cb + ((size_t)q * K_ + k) * D_;
            double a = 0.0;
            for (int d = 0; d < D_; ++d)
                a = fma((double)Ek[d], (double)r32T[d][j], a);
            float V = srb[j] + Se[q * K_ + k];
            sdd[j][s] = V - 2.0f * (float)a;           // true dd (correctly-rounded dot)
        }
    }
    __syncthreads();
    if (tid < R_) {
        int cnt = scount[tid];
        if (cnt == 1) sidx[tid] = slist[tid][0];
        else if (cnt <= 16) {
            float bd = 3.4e38f; int bk = 0x7fffffff;
            for (int s2 = 0; s2 < cnt; ++s2) {
                float dv = sdd[tid][s2]; int kv = slist[tid][s2];
                if (dv < bd || (dv == bd && kv < bk)) { bd = dv; bk = kv; }
            }
            sidx[tid] = bk;
        }
    }
    __syncthreads();

    // overflow fallback (>16 survivors; practically unreachable but exact)
    for (int j = 0; j < R_; ++j) {
        if (scount[j] > 16) {
            const float* Eqt = Et + (size_t)q * D_ * K_;
            float bd = 3.4e38f; int bk = K_;
            #pragma unroll
            for (int c = 0; c < C_; ++c) {
                int k = 4 * tid + c;
                double a = 0.0;
                for (int d = 0; d < D_; ++d)
                    a = fma((double)Eqt[(size_t)d * K_ + k], (double)r32T[d][j], a);
                float ddx = (srb[j] + Se[q * K_ + k]) - 2.0f * (float)a;
                if (ddx < bd || (ddx == bd && k < bk)) { bd = ddx; bk = k; }
            }
            u.f8[0][tid] = bd; ((int*)u.f8[1])[tid] = bk;
            __syncthreads();
            for (int s = 128; s > 0; s >>= 1) {
                if (tid < s) {
                    float od = u.f8[0][tid + s]; int ok = ((int*)u.f8[1])[tid + s];
                    if (od < u.f8[0][tid] ||
                        (od == u.f8[0][tid] && ok < ((int*)u.f8[1])[tid])) {
                        u.f8[0][tid] = od; ((int*)u.f8[1])[tid] = ok;
                    }
                }
                __syncthreads();
            }
            if (tid == 0) sidx[j] = ((int*)u.f8[1])[0];
            __syncthreads();
        }
    }

    // epilogue: exact fp32 STE residual update (bitwise as prior rounds)
    const float* Eq = cb + (size_t)q * K_ * D_;
    double lsum = 0.0;
    #pragma unroll
    for (int j = 0; j < R_; ++j) {
        int idx = sidx[j];
        float rv   = r32T[tid][j];
        float zq   = Eq[(size_t)idx * D_ + tid];       // coalesced
        float t1   = zq - rv;                          // fl(z_q - r)
        float zqst = rv + t1;                          // fl(r + fl(z_q - r))
        residual[(size_t)(row0 + j) * D_ + tid] = rv - zqst;
        lsum += (double)t1 * (double)t1;
    }
    if (tid < R_) out[IDX_OFF + q * BT_ + row0 + tid] = (float)sidx[tid];

    __syncthreads();
    u.d8[0][tid] = lsum;
    __syncthreads();
    for (int s = 128; s > 0; s >>= 1) {
        if (tid < s) u.d8[0][tid] += u.d8[0][tid + s];
        __syncthreads();
    }
    if (tid == 0) atomicAdd(lossAcc, u.d8[0][0]);
}

// ---------------- emit: out[b,d,t] = z[b,d,t] - r_final[b,t,d] ----------------

__global__ void k_emit(const float* __restrict__ z, const float* __restrict__ residual,
                       float* __restrict__ out) {
    __shared__ float tile[32][33];
    int b  = blockIdx.z;
    int t0 = blockIdx.y * 32;
    int d0 = blockIdx.x * 32;
    int tx = threadIdx.x & 31;
    int ty = threadIdx.x >> 5;
    const float* rb = residual + (size_t)b * T_ * D_;
    #pragma unroll
    for (int r = 0; r < 32; r += 8)
        tile[ty + r][tx] = rb[(size_t)(t0 + ty + r) * D_ + d0 + tx];   // tile[t][d]
    __syncthreads();
    const float* zb = z + (size_t)b * D_ * T_;
    float* ob = out + (size_t)b * D_ * T_;
    #pragma unroll
    for (int r = 0; r < 32; r += 8) {
        size_t off = (size_t)(d0 + ty + r) * T_ + t0 + tx;
        ob[off] = zb[off] - tile[tx][ty + r];
    }
}

__global__ void k_final(const double* lossAcc, float* out) {
    if (threadIdx.x == 0 && blockIdx.x == 0) {
        double m = *lossAcc / (double)N_;
        out[LOSS_OFF] = (float)(1.25 * m);
    }
}

// ---------------- launcher ----------------

extern "C" void kernel_launch(void* const* d_in, const int* in_sizes, int n_in,
                              void* d_out, int out_size, void* d_ws, size_t ws_size,
                              hipStream_t stream) {
    const float* z  = (const float*)d_in[0];
    const float* cb = (const float*)d_in[1];
    float* out = (float*)d_out;

    // ws layout: residual f32[N_] | Et f32[Q*D*K] (8MB) | Se f32[Q*K] | loss double
    float*  residual = (float*)d_ws;
    float*  Et       = (float*)((char*)d_ws + (size_t)N_ * 4);
    float*  Se       = (float*)((char*)d_ws + (size_t)N_ * 4 + (size_t)Q_ * D_ * K_ * 4);
    double* lossAcc  = (double*)((char*)d_ws + (size_t)N_ * 4 + (size_t)Q_ * D_ * K_ * 4
                                 + (size_t)Q_ * K_ * 4);

    hipLaunchKernelGGL(k_init, dim3(T_ / 32, D_ / 32, B_), dim3(256), 0, stream,
                       z, residual, lossAcc);
    hipLaunchKernelGGL(k_et, dim3(D_ / 32, K_ / 32, Q_), dim3(256), 0, stream, cb, Et);
    hipLaunchKernelGGL(k_se, dim3((Q_ * K_ + 255) / 256), dim3(256), 0, stream, cb, Se);
    for (int q = 0; q < Q_; ++q) {
        hipLaunchKernelGGL(k_stage, dim3(BT_ / R_), dim3(256), 0, stream,
                           cb, Et, Se, residual, out, lossAcc, q);
    }
    hipLaunchKernelGGL(k_emit, dim3(D_ / 32, T_ / 32, B_), dim3(256), 0, stream,
                       z, residual, out);
    hipLaunchKernelGGL(k_final, dim3(1), dim3(256), 0, stream, lossAcc, out);
}

// Round 6
// 1105.245 us; speedup vs baseline: 26.2674x; 1.7962x over previous
//
#include <hip/hip_runtime.h>

#define B_   8
#define D_   256
#define T_   4096
#define Q_   8
#define K_   1024
#define BT_  (B_*T_)            // 32768 rows
#define N_   (B_*T_*D_)         // 8388608 elements
#define LOSS_OFF N_
#define IDX_OFF  (N_+1)
#define ROWS 32                 // rows per block
#define RP   260                // padded row stride in LDS floats

typedef __attribute__((ext_vector_type(8))) short short8;
typedef __attribute__((ext_vector_type(4))) float float4v;

union U4S8 { uint4 u; short8 s; };

__device__ __forceinline__ unsigned short f2bf(float x) {
    unsigned int u = __float_as_uint(x);
    unsigned int r = (u + 0x7FFFu + ((u >> 16) & 1u)) >> 16;
    return (unsigned short)r;
}
__device__ __forceinline__ float bf2f(unsigned short b) {
    return __uint_as_float(((unsigned int)b) << 16);
}

// ---------------- init: z [B,D,T] -> residual [B,T,D], tiled transpose ----------------

__global__ void k_init(const float* __restrict__ z, float* __restrict__ residual,
                       double* lossAcc) {
    __shared__ float tile[32][33];
    int b  = blockIdx.z;
    int d0 = blockIdx.y * 32;
    int t0 = blockIdx.x * 32;
    int tx = threadIdx.x & 31;
    int ty = threadIdx.x >> 5;
    const float* zb = z + (size_t)b * D_ * T_;
    #pragma unroll
    for (int r = 0; r < 32; r += 8)
        tile[ty + r][tx] = zb[(size_t)(d0 + ty + r) * T_ + t0 + tx];
    __syncthreads();
    float* rb = residual + (size_t)b * T_ * D_;
    #pragma unroll
    for (int r = 0; r < 32; r += 8)
        rb[(size_t)(t0 + ty + r) * D_ + d0 + tx] = tile[tx][ty + r];
    if (b == 0 && blockIdx.x == 0 && blockIdx.y == 0 && threadIdx.x == 0)
        *lossAcc = 0.0;
}

// ---------------- B-fragment precompute: cb -> bf16 hi/lo in MFMA lane layout ----------
// Layout: Bfrag[((q*64 + ct)*8 + kc)*2*64 + part*64 + lane] : uint4 (8 bf16)
// lane supplies B[k = kc*32 + (lane>>4)*8 + j][n = ct*16 + (lane&15)], j=0..7

__global__ void k_bfrag(const float* __restrict__ cb, uint4* __restrict__ Bfrag) {
    int gid = blockIdx.x * 256 + threadIdx.x;      // 262144 total
    int q    = gid >> 15;
    int rem  = gid & 32767;
    int ct   = rem >> 9;
    int kc   = (rem >> 6) & 7;
    int lane = rem & 63;
    int cand = ct * 16 + (lane & 15);
    int kb   = kc * 32 + (lane >> 4) * 8;
    const float* e = cb + ((size_t)q * K_ + cand) * D_ + kb;
    unsigned short h[8], l[8];
    #pragma unroll
    for (int j = 0; j < 8; ++j) {
        float v = e[j];
        h[j] = f2bf(v);
        l[j] = f2bf(v - bf2f(h[j]));
    }
    uint4 hi, lo;
    hi.x = (unsigned)h[0] | ((unsigned)h[1] << 16);
    hi.y = (unsigned)h[2] | ((unsigned)h[3] << 16);
    hi.z = (unsigned)h[4] | ((unsigned)h[5] << 16);
    hi.w = (unsigned)h[6] | ((unsigned)h[7] << 16);
    lo.x = (unsigned)l[0] | ((unsigned)l[1] << 16);
    lo.y = (unsigned)l[2] | ((unsigned)l[3] << 16);
    lo.z = (unsigned)l[4] | ((unsigned)l[5] << 16);
    lo.w = (unsigned)l[6] | ((unsigned)l[7] << 16);
    size_t base = (((size_t)(q * 64 + ct) * 8 + kc) * 2) * 64;
    Bfrag[base + lane]      = hi;
    Bfrag[base + 64 + lane] = lo;
}

// ---------------- S_e: fp64 sum of fl32(e^2), rounded to f32 ----------------

__global__ void k_se(const float* __restrict__ cb, float* __restrict__ Se) {
    int i = blockIdx.x * 256 + threadIdx.x;
    if (i >= Q_ * K_) return;
    const float* e = cb + (size_t)i * D_;
    double s = 0.0;
    for (int d = 0; d < D_; ++d) {
        float v = e[d];
        float a = v * v;
        s += (double)a;
    }
    Se[i] = (float)s;
}

// ---------------- per-stage kernel: MFMA bf16-split filter + fp64 re-rank --------------

__launch_bounds__(512)
__global__ void k_stage(const float* __restrict__ cb,
                        const uint4* __restrict__ Bfrag,
                        const float* __restrict__ Se,
                        float* __restrict__ residual,
                        float* __restrict__ out,
                        double* __restrict__ lossAcc,
                        int q) {
    __shared__ float r32[ROWS][RP];                       // 33.3 KB
    __shared__ union {
        uint4 afr[2048];                                  // 32 KB A-frags (filter phase)
        struct { double sred[32][16]; float sabr[32][16]; } pro;   // prologue
        struct { int slist[32][16]; float sdd[32][16];
                 float ovd[512]; int ovk[512]; } post;    // post-filter
        double lred[512];                                 // loss tree
    } sc;
    __shared__ float seL[1024];                           // 4 KB
    __shared__ float srb[32], thr[32], smin[32];
    __shared__ float sminP[32][8];
    __shared__ int   scount[32], sidx[32];

    const int tid  = threadIdx.x;
    const int lane = tid & 63;
    const int w    = tid >> 6;          // wave 0..7
    const int quad = lane >> 4;
    const int lc   = lane & 15;
    const int row0 = blockIdx.x * ROWS;
    const int g    = tid >> 8;          // half-block 0/1
    const int dt   = tid & 255;

    // ---- load residual rows (coalesced) ----
    #pragma unroll
    for (int jj = 0; jj < 16; ++jj) {
        int row = g * 16 + jj;
        r32[row][dt] = residual[(size_t)(row0 + row) * D_ + dt];
    }
    if (tid < 32) scount[tid] = 0;
    // stage Se
    seL[tid]       = Se[q * K_ + tid];
    seL[tid + 512] = Se[q * K_ + tid + 512];
    __syncthreads();

    // ---- Sr (fp64 exact) and Sum|r| per row ----
    {
        int row = tid >> 4, seg = tid & 15;
        const float* rp = &r32[row][seg * 16];
        double s = 0.0; float sa = 0.0f;
        #pragma unroll
        for (int i = 0; i < 16; ++i) {
            float v = rp[i];
            s += (double)(v * v);
            sa += fabsf(v);
        }
        sc.pro.sred[row][seg] = s;
        sc.pro.sabr[row][seg] = sa;
        __syncthreads();
        for (int st = 8; st > 0; st >>= 1) {
            if (seg < st) {
                sc.pro.sred[row][seg] += sc.pro.sred[row][seg + st];
                sc.pro.sabr[row][seg] += sc.pro.sabr[row][seg + st];
            }
            __syncthreads();
        }
        if (tid < 32) {
            float sr = (float)sc.pro.sred[tid][0];
            float sb = sc.pro.sabr[tid][0] * 1.001f;
            srb[tid] = sr;
            thr[tid] = 9.6e-7f * sr + 4.0e-7f * sb + 2.0e-4f;   // margin (smin added later)
        }
        __syncthreads();
    }

    // ---- build A-frags (r hi/lo bf16) in LDS, MFMA lane layout ----
    // afr[((rg*8+kc)*2+part)*64 + ln]; lane supplies A[m=ln&15 (+16rg)][k=kc*32+(ln>>4)*8+j]
    #pragma unroll
    for (int half = 0; half < 2; ++half) {
        int s = tid + half * 512;
        int rg = s >> 9, kc = (s >> 6) & 7, ln = s & 63;
        int row = rg * 16 + (ln & 15);
        int kb  = kc * 32 + (ln >> 4) * 8;
        unsigned short h[8], l[8];
        #pragma unroll
        for (int j = 0; j < 8; ++j) {
            float v = r32[row][kb + j];
            h[j] = f2bf(v);
            l[j] = f2bf(v - bf2f(h[j]));
        }
        uint4 hi, lo;
        hi.x = (unsigned)h[0] | ((unsigned)h[1] << 16);
        hi.y = (unsigned)h[2] | ((unsigned)h[3] << 16);
        hi.z = (unsigned)h[4] | ((unsigned)h[5] << 16);
        hi.w = (unsigned)h[6] | ((unsigned)h[7] << 16);
        lo.x = (unsigned)l[0] | ((unsigned)l[1] << 16);
        lo.y = (unsigned)l[2] | ((unsigned)l[3] << 16);
        lo.z = (unsigned)l[4] | ((unsigned)l[5] << 16);
        lo.w = (unsigned)l[6] | ((unsigned)l[7] << 16);
        sc.afr[((rg * 8 + kc) * 2 + 0) * 64 + ln] = hi;
        sc.afr[((rg * 8 + kc) * 2 + 1) * 64 + ln] = lo;
    }
    __syncthreads();

    // ---- MFMA filter: wave w covers cand-tiles w*8..w*8+7, both row-groups ----
    float4v accA[16];
    #pragma unroll
    for (int i = 0; i < 16; ++i) accA[i] = (float4v){0.f, 0.f, 0.f, 0.f};

    const uint4* Bq = Bfrag + (size_t)q * (64 * 8 * 2 * 64);
    for (int kc = 0; kc < 8; ++kc) {
        U4S8 a0h, a0l, a1h, a1l;
        a0h.u = sc.afr[((0 * 8 + kc) * 2 + 0) * 64 + lane];
        a0l.u = sc.afr[((0 * 8 + kc) * 2 + 1) * 64 + lane];
        a1h.u = sc.afr[((1 * 8 + kc) * 2 + 0) * 64 + lane];
        a1l.u = sc.afr[((1 * 8 + kc) * 2 + 1) * 64 + lane];
        #pragma unroll
        for (int ctl = 0; ctl < 8; ++ctl) {
            int ct = w * 8 + ctl;
            const uint4* Bt = Bq + ((size_t)(ct * 8 + kc) * 2) * 64;
            U4S8 bh, bl;
            bh.u = Bt[lane];
            bl.u = Bt[64 + lane];
            float4v a0 = accA[ctl * 2 + 0];
            a0 = __builtin_amdgcn_mfma_f32_16x16x32_bf16(a0h.s, bh.s, a0, 0, 0, 0);
            a0 = __builtin_amdgcn_mfma_f32_16x16x32_bf16(a0l.s, bh.s, a0, 0, 0, 0);
            a0 = __builtin_amdgcn_mfma_f32_16x16x32_bf16(a0h.s, bl.s, a0, 0, 0, 0);
            accA[ctl * 2 + 0] = a0;
            float4v a1 = accA[ctl * 2 + 1];
            a1 = __builtin_amdgcn_mfma_f32_16x16x32_bf16(a1h.s, bh.s, a1, 0, 0, 0);
            a1 = __builtin_amdgcn_mfma_f32_16x16x32_bf16(a1l.s, bh.s, a1, 0, 0, 0);
            a1 = __builtin_amdgcn_mfma_f32_16x16x32_bf16(a1h.s, bl.s, a1, 0, 0, 0);
            accA[ctl * 2 + 1] = a1;
        }
    }

    // ---- per-lane mins over tiles; D layout: row = rg*16 + quad*4 + reg, col = lc ----
    float sr8[8];
    #pragma unroll
    for (int rr = 0; rr < 8; ++rr)
        sr8[rr] = srb[(rr >> 2) * 16 + quad * 4 + (rr & 3)];

    float mn[8];
    #pragma unroll
    for (int rr = 0; rr < 8; ++rr) mn[rr] = 3.4e38f;
    #pragma unroll
    for (int ctl = 0; ctl < 8; ++ctl) {
        int cand = (w * 8 + ctl) * 16 + lc;
        float se = seL[cand];
        #pragma unroll
        for (int rr = 0; rr < 8; ++rr) {
            float dd = (sr8[rr] + se) - 2.0f * accA[ctl * 2 + (rr >> 2)][rr & 3];
            mn[rr] = fminf(mn[rr], dd);
        }
    }
    #pragma unroll
    for (int rr = 0; rr < 8; ++rr) {
        float v = mn[rr];
        v = fminf(v, __shfl_xor(v, 1));
        v = fminf(v, __shfl_xor(v, 2));
        v = fminf(v, __shfl_xor(v, 4));
        v = fminf(v, __shfl_xor(v, 8));
        if (lc == 0) sminP[(rr >> 2) * 16 + quad * 4 + (rr & 3)][w] = v;
    }
    __syncthreads();
    if (tid < 32) {
        float m = sminP[tid][0];
        #pragma unroll
        for (int i = 1; i < 8; ++i) m = fminf(m, sminP[tid][i]);
        smin[tid] = m;
        thr[tid] = m + thr[tid];
    }
    __syncthreads();

    // ---- survivor collection ----
    #pragma unroll
    for (int ctl = 0; ctl < 8; ++ctl) {
        int cand = (w * 8 + ctl) * 16 + lc;
        float se = seL[cand];
        #pragma unroll
        for (int rr = 0; rr < 8; ++rr) {
            int row = (rr >> 2) * 16 + quad * 4 + (rr & 3);
            float dd = (sr8[rr] + se) - 2.0f * accA[ctl * 2 + (rr >> 2)][rr & 3];
            if (dd <= thr[row]) {
                int p = atomicAdd(&scount[row], 1);
                if (p < 16) sc.post.slist[row][p] = cand;
            }
        }
    }
    __syncthreads();

    // ---- exact fp64 re-rank of survivors (2..16 per row) ----
    {
        int row = tid >> 4, slot = tid & 15;
        int cnt = scount[row];
        if (cnt >= 2 && cnt <= 16 && slot < cnt) {
            int k = sc.post.slist[row][slot];
            const float* Ek = cb + ((size_t)q * K_ + k) * D_;
            double a0 = 0.0, a1 = 0.0;
            for (int d = 0; d < D_; d += 2) {
                a0 = fma((double)Ek[d],     (double)r32[row][d],     a0);
                a1 = fma((double)Ek[d + 1], (double)r32[row][d + 1], a1);
            }
            float dotf = (float)(a0 + a1);
            float V = srb[row] + seL[k];
            sc.post.sdd[row][slot] = V - 2.0f * dotf;
        }
    }
    __syncthreads();
    if (tid < 32) {
        int cnt = scount[tid];
        if (cnt == 1) sidx[tid] = sc.post.slist[tid][0];
        else if (cnt <= 16) {
            float bd = 3.4e38f; int bk = 0x7fffffff;
            for (int s2 = 0; s2 < cnt; ++s2) {
                float dv = sc.post.sdd[tid][s2]; int kv = sc.post.slist[tid][s2];
                if (dv < bd || (dv == bd && kv < bk)) { bd = dv; bk = kv; }
            }
            sidx[tid] = bk;
        }
    }
    __syncthreads();

    // ---- overflow fallback (>16 survivors; exact, block-wide, rare) ----
    for (int row = 0; row < ROWS; ++row) {
        int cnt = scount[row];
        if (cnt <= 16) continue;
        float bd = 3.4e38f; int bk = K_;
        #pragma unroll
        for (int c = 0; c < 2; ++c) {
            int k = tid * 2 + c;
            const float* Ek = cb + ((size_t)q * K_ + k) * D_;
            double a0 = 0.0, a1 = 0.0;
            for (int d = 0; d < D_; d += 2) {
                a0 = fma((double)Ek[d],     (double)r32[row][d],     a0);
                a1 = fma((double)Ek[d + 1], (double)r32[row][d + 1], a1);
            }
            float dd = (srb[row] + seL[k]) - 2.0f * (float)(a0 + a1);
            if (dd < bd || (dd == bd && k < bk)) { bd = dd; bk = k; }
        }
        sc.post.ovd[tid] = bd; sc.post.ovk[tid] = bk;
        __syncthreads();
        for (int st = 256; st > 0; st >>= 1) {
            if (tid < st) {
                float od = sc.post.ovd[tid + st]; int ok = sc.post.ovk[tid + st];
                if (od < sc.post.ovd[tid] ||
                    (od == sc.post.ovd[tid] && ok < sc.post.ovk[tid])) {
                    sc.post.ovd[tid] = od; sc.post.ovk[tid] = ok;
                }
            }
            __syncthreads();
        }
        if (tid == 0) sidx[row] = sc.post.ovk[0];
        __syncthreads();
    }

    // ---- epilogue: exact fp32 STE residual update (bitwise as prior rounds) ----
    const float* Eq = cb + (size_t)q * K_ * D_;
    double lsum = 0.0;
    #pragma unroll
    for (int jj = 0; jj < 16; ++jj) {
        int row = g * 16 + jj;
        int idx = sidx[row];
        float rv   = r32[row][dt];
        float zq   = Eq[(size_t)idx * D_ + dt];
        float t1   = zq - rv;
        float zqst = rv + t1;
        residual[(size_t)(row0 + row) * D_ + dt] = rv - zqst;
        lsum += (double)t1 * (double)t1;
    }
    if (tid < 32) out[IDX_OFF + q * BT_ + row0 + tid] = (float)sidx[tid];

    __syncthreads();
    sc.lred[tid] = lsum;
    __syncthreads();
    for (int st = 256; st > 0; st >>= 1) {
        if (tid < st) sc.lred[tid] += sc.lred[tid + st];
        __syncthreads();
    }
    if (tid == 0) atomicAdd(lossAcc, sc.lred[0]);
}

// ---------------- emit: out[b,d,t] = z[b,d,t] - r_final[b,t,d] ----------------

__global__ void k_emit(const float* __restrict__ z, const float* __restrict__ residual,
                       float* __restrict__ out) {
    __shared__ float tile[32][33];
    int b  = blockIdx.z;
    int t0 = blockIdx.y * 32;
    int d0 = blockIdx.x * 32;
    int tx = threadIdx.x & 31;
    int ty = threadIdx.x >> 5;
    const float* rb = residual + (size_t)b * T_ * D_;
    #pragma unroll
    for (int r = 0; r < 32; r += 8)
        tile[ty + r][tx] = rb[(size_t)(t0 + ty + r) * D_ + d0 + tx];
    __syncthreads();
    const float* zb = z + (size_t)b * D_ * T_;
    float* ob = out + (size_t)b * D_ * T_;
    #pragma unroll
    for (int r = 0; r < 32; r += 8) {
        size_t off = (size_t)(d0 + ty + r) * T_ + t0 + tx;
        ob[off] = zb[off] - tile[tx][ty + r];
    }
}

__global__ void k_final(const double* lossAcc, float* out) {
    if (threadIdx.x == 0 && blockIdx.x == 0) {
        double m = *lossAcc / (double)N_;
        out[LOSS_OFF] = (float)(1.25 * m);
    }
}

// ---------------- launcher ----------------

extern "C" void kernel_launch(void* const* d_in, const int* in_sizes, int n_in,
                              void* d_out, int out_size, void* d_ws, size_t ws_size,
                              hipStream_t stream) {
    const float* z  = (const float*)d_in[0];
    const float* cb = (const float*)d_in[1];
    float* out = (float*)d_out;

    // ws layout: residual f32[N_] (32MB) | Bfrag uint4 (8MB) | Se f32[Q*K] | loss double
    float*  residual = (float*)d_ws;
    uint4*  Bfrag    = (uint4*)((char*)d_ws + (size_t)N_ * 4);
    float*  Se       = (float*)((char*)d_ws + (size_t)N_ * 4 + (size_t)8 * 1024 * 1024);
    double* lossAcc  = (double*)((char*)d_ws + (size_t)N_ * 4 + (size_t)8 * 1024 * 1024
                                 + (size_t)Q_ * K_ * 4);

    hipLaunchKernelGGL(k_init, dim3(T_ / 32, D_ / 32, B_), dim3(256), 0, stream,
                       z, residual, lossAcc);
    hipLaunchKernelGGL(k_bfrag, dim3(1024), dim3(256), 0, stream, cb, Bfrag);
    hipLaunchKernelGGL(k_se, dim3((Q_ * K_ + 255) / 256), dim3(256), 0, stream, cb, Se);
    for (int q = 0; q < Q_; ++q) {
        hipLaunchKernelGGL(k_stage, dim3(BT_ / ROWS), dim3(512), 0, stream,
                           cb, Bfrag, Se, residual, out, lossAcc, q);
    }
    hipLaunchKernelGGL(k_emit, dim3(D_ / 32, T_ / 32, B_), dim3(256), 0, stream,
                       z, residual, out);
    hipLaunchKernelGGL(k_final, dim3(1), dim3(256), 0, stream, lossAcc, out);
}